// Round 16
// baseline (357.103 us; speedup 1.0000x reference)
//
#include <hip/hip_runtime.h>
#include <stdint.h>

#define B_ 128
#define T_ 1000
#define H_ 512
#define PH 8          // steps per phase
#define NPHASE 125    // T_/PH

typedef float vfloat4 __attribute__((ext_vector_type(4)));
typedef float vfloat2 __attribute__((ext_vector_type(2)));

template <int CTRL>
__device__ __forceinline__ float dpp_add(float x) {
    int moved = __builtin_amdgcn_update_dpp(0, __float_as_int(x), CTRL, 0xf, 0xf, true);
    return x + __int_as_float(moved);
}

__device__ __forceinline__ void wave_reduce2(float& p0, float& p1) {
    p0 = dpp_add<0x111>(p0); p1 = dpp_add<0x111>(p1);
    p0 = dpp_add<0x112>(p0); p1 = dpp_add<0x112>(p1);
    p0 = dpp_add<0x114>(p0); p1 = dpp_add<0x114>(p1);
    p0 = dpp_add<0x118>(p0); p1 = dpp_add<0x118>(p1);
    p0 = dpp_add<0x142>(p0); p1 = dpp_add<0x142>(p1);
    p0 = dpp_add<0x143>(p0); p1 = dpp_add<0x143>(p1);
}

__device__ __forceinline__ void wave_reduce4(float& a, float& b, float& c, float& d) {
    a = dpp_add<0x111>(a); b = dpp_add<0x111>(b); c = dpp_add<0x111>(c); d = dpp_add<0x111>(d);
    a = dpp_add<0x112>(a); b = dpp_add<0x112>(b); c = dpp_add<0x112>(c); d = dpp_add<0x112>(d);
    a = dpp_add<0x114>(a); b = dpp_add<0x114>(b); c = dpp_add<0x114>(c); d = dpp_add<0x114>(d);
    a = dpp_add<0x118>(a); b = dpp_add<0x118>(b); c = dpp_add<0x118>(c); d = dpp_add<0x118>(d);
    a = dpp_add<0x142>(a); b = dpp_add<0x142>(b); c = dpp_add<0x142>(c); d = dpp_add<0x142>(d);
    a = dpp_add<0x143>(a); b = dpp_add<0x143>(b); c = dpp_add<0x143>(c); d = dpp_add<0x143>(d);
}

__device__ __forceinline__ float wave_reduce1(float p) {
    p = dpp_add<0x111>(p); p = dpp_add<0x112>(p); p = dpp_add<0x114>(p);
    p = dpp_add<0x118>(p); p = dpp_add<0x142>(p); p = dpp_add<0x143>(p);
    return p;
}

__device__ __forceinline__ float fast_tanh(float x) {
    float E = __builtin_amdgcn_exp2f(x * 2.885390081777927f);
    float r = __builtin_amdgcn_rcpf(E + 1.0f);
    return __builtin_fmaf(-2.0f, r, 1.0f);
}

#define C2_ 2.885390081777927f
#define RL63(x) __int_as_float(__builtin_amdgcn_readlane(__float_as_int(x), 63))

__device__ __forceinline__ vfloat2 bc2(float x) { vfloat2 v = {x, x}; return v; }
__device__ __forceinline__ vfloat2 th2(vfloat2 b) {   // packed tanh via exp2+rcp
    vfloat2 x2 = b * C2_;
    vfloat2 E  = {__builtin_amdgcn_exp2f(x2.x), __builtin_amdgcn_exp2f(x2.y)};
    vfloat2 D  = E + 1.0f;
    vfloat2 R  = {__builtin_amdgcn_rcpf(D.x), __builtin_amdgcn_rcpf(D.y)};
    return bc2(-2.0f) * R + 1.0f;
}

__global__ __launch_bounds__(128, 1) void lowrank_rnn_kernel(
    const float* __restrict__ input, const float* __restrict__ noise,
    const float* __restrict__ wi, const float* __restrict__ si,
    const float* __restrict__ m, const float* __restrict__ n,
    const float* __restrict__ wo, const float* __restrict__ so,
    const float* __restrict__ h0, float* __restrict__ out)
{
    const int b    = blockIdx.x;
    const int tid  = threadIdx.x;
    const int wid  = tid >> 6;
    const int lane = tid & 63;
    const int j0   = lane * 8;

    __shared__ __align__(16) vfloat4 ub[2][PH][2][64];
    __shared__ __align__(16) vfloat4 rb[2][PH][2][64];
    __shared__ __align__(16) vfloat4 hb[2][PH][2][64];
    __shared__ __align__(16) vfloat4 rfin[2][64];
    __shared__ __align__(16) vfloat4 hfin[2][64];
    __shared__ float os[T_ + 1];
    __shared__ int   flags[2];

    if (tid == 0) { flags[0] = 0; flags[1] = 0; }
    __syncthreads();
    volatile int* vprod = &flags[0];
    volatile int* vcons = &flags[1];

    if (wid == 1) {
        // ========== PRODUCER (verbatim R14) ==========
        float wS0[8], wS1[8], wS2[8], wof[8];
        {
            const float so0 = so[0];
            #pragma unroll
            for (int i = 0; i < 3; ++i) {
                float s = 0.2f * si[i];
                float* dst = (i == 0) ? wS0 : (i == 1) ? wS1 : wS2;
                #pragma unroll
                for (int q = 0; q < 2; ++q) {
                    vfloat4 vw = *(const vfloat4*)(wi + i * H_ + j0 + 4 * q);
                    dst[4*q] = vw.x * s; dst[4*q+1] = vw.y * s;
                    dst[4*q+2] = vw.z * s; dst[4*q+3] = vw.w * s;
                }
            }
            #pragma unroll
            for (int q = 0; q < 2; ++q) {
                vfloat4 vw = *(const vfloat4*)(wo + j0 + 4 * q);
                wof[4*q] = vw.x * so0; wof[4*q+1] = vw.y * so0;
                wof[4*q+2] = vw.z * so0; wof[4*q+3] = vw.w * so0;
            }
        }
        const float* zb = noise + (size_t)b * T_ * H_ + j0;
        const float* xb = input + (size_t)b * T_ * 3;
        float* trajBase = out + (size_t)B_ * T_ + (size_t)b * (T_ + 1) * H_;

        {
            vfloat4 a = *(const vfloat4*)(h0 + j0);
            vfloat4 c = *(const vfloat4*)(h0 + j0 + 4);
            *(vfloat4*)(trajBase + j0)     = a;
            *(vfloat4*)(trajBase + j0 + 4) = c;
        }

        auto emit_phase = [&](int pp) {
            const int hf = pp & 1;
            #pragma unroll
            for (int s = 0; s < PH; ++s) {
                const int t = pp * PH + s;
                vfloat4 rl = rb[hf][s][0][lane];
                vfloat4 rh = rb[hf][s][1][lane];
                float p2 = rl.x * wof[0];
                p2 = __builtin_fmaf(rl.y, wof[1], p2);
                p2 = __builtin_fmaf(rl.z, wof[2], p2);
                p2 = __builtin_fmaf(rl.w, wof[3], p2);
                p2 = __builtin_fmaf(rh.x, wof[4], p2);
                p2 = __builtin_fmaf(rh.y, wof[5], p2);
                p2 = __builtin_fmaf(rh.z, wof[6], p2);
                p2 = __builtin_fmaf(rh.w, wof[7], p2);
                p2 = wave_reduce1(p2);
                if (lane == 63) os[t] = p2;
                vfloat4 hl = hb[hf][s][0][lane];
                vfloat4 hh = hb[hf][s][1][lane];
                float* tr = trajBase + (size_t)t * H_ + j0;
                *(vfloat4*)tr       = hl;
                *(vfloat4*)(tr + 4) = hh;
            }
        };

        for (int q = 0; q < NPHASE; ++q) {
            if (q >= 2) {
                while (*vcons < q - 1) {}
                asm volatile("" ::: "memory");
            }
            vfloat4 zl[PH], zh[PH];
            #pragma unroll
            for (int s = 0; s < PH; ++s) {
                const float* g = zb + (size_t)(q * PH + s) * H_;
                zl[s] = *(const vfloat4*)g;
                zh[s] = *(const vfloat4*)(g + 4);
            }
            if (q >= 2) emit_phase(q - 2);
            const int half = q & 1;
            #pragma unroll
            for (int s = 0; s < PH; ++s) {
                const int t = q * PH + s;
                float x0 = xb[3*t], x1 = xb[3*t+1], x2 = xb[3*t+2];
                float zz[8] = {zl[s].x, zl[s].y, zl[s].z, zl[s].w,
                               zh[s].x, zh[s].y, zh[s].z, zh[s].w};
                float u[8];
                #pragma unroll
                for (int k = 0; k < 8; ++k) {
                    float xw = __builtin_fmaf(x0, wS0[k],
                               __builtin_fmaf(x1, wS1[k], x2 * wS2[k]));
                    u[k] = __builtin_fmaf(zz[k], 0.05f, xw);
                }
                vfloat4 ulo = {u[0], u[1], u[2], u[3]};
                vfloat4 uhi = {u[4], u[5], u[6], u[7]};
                ub[half][s][0][lane] = ulo;
                ub[half][s][1][lane] = uhi;
            }
            asm volatile("s_waitcnt lgkmcnt(0)" ::: "memory");
            if (lane == 0) *vprod = q + 1;
        }
        while (*vcons < NPHASE) {}
        asm volatile("" ::: "memory");
        emit_phase(NPHASE - 2);
        emit_phase(NPHASE - 1);
        while (*vcons < NPHASE + 1) {}
        asm volatile("" ::: "memory");
        {
            vfloat4 rl = rfin[0][lane], rh = rfin[1][lane];
            float p2 = rl.x * wof[0];
            p2 = __builtin_fmaf(rl.y, wof[1], p2);
            p2 = __builtin_fmaf(rl.z, wof[2], p2);
            p2 = __builtin_fmaf(rl.w, wof[3], p2);
            p2 = __builtin_fmaf(rh.x, wof[4], p2);
            p2 = __builtin_fmaf(rh.y, wof[5], p2);
            p2 = __builtin_fmaf(rh.z, wof[6], p2);
            p2 = __builtin_fmaf(rh.w, wof[7], p2);
            p2 = wave_reduce1(p2);
            if (lane == 63) os[T_] = p2;
            float* tr = trajBase + (size_t)T_ * H_ + j0;
            *(vfloat4*)tr       = hfin[0][lane];
            *(vfloat4*)(tr + 4) = hfin[1][lane];
        }
        asm volatile("s_waitcnt lgkmcnt(0)" ::: "memory");
        float* outp = out + (size_t)b * T_;
        for (int idx = lane; idx < T_; idx += 64)
            outp[idx] = os[idx + 1];
    } else {
        // ========== CONSUMER: scalar affine a-recurrence, reduces pipelined 2-deep ==========
        vfloat2 m0S[4], m1S[4], n0v[4], n1v[4];
        vfloat2 basep[4], Tk0[4], Tk1[4], Dk0[4], Dk1[4], ucur[4];
        float cA0=0, cA1=0, cB0=0, cB1=0, qa0=0, qa1=0, qa2=0, qa3=0;
        float A00, A01, A10, A11;
        float a1_0, a1_1, a2_0, a2_1, C0cur, C1cur;
        vfloat2 h0v[4];
        {
            const float* nb = n + 2 * j0;
            const float* mb = m + 2 * j0;
            #pragma unroll
            for (int q = 0; q < 4; ++q) {
                vfloat4 vn = *(const vfloat4*)(nb + 4 * q);
                vfloat2 a = {vn.x, vn.z}; n0v[q] = a;
                vfloat2 c = {vn.y, vn.w}; n1v[q] = c;
                vfloat4 vm = *(const vfloat4*)(mb + 4 * q);
                vfloat2 d = {0.2f * vm.x, 0.2f * vm.z}; m0S[q] = d;
                vfloat2 e = {0.2f * vm.y, 0.2f * vm.w}; m1S[q] = e;
            }
            #pragma unroll
            for (int q = 0; q < 2; ++q) {
                vfloat4 vh = *(const vfloat4*)(h0 + j0 + 4 * q);
                vfloat2 lo = {vh.x, vh.y}, hi = {vh.z, vh.w};
                h0v[2*q] = lo; h0v[2*q+1] = hi;
            }
        }
        #define HORIZ(dst, A_, B_) { \
            vfloat2 q01_ = A_[1]*B_[1] + A_[0]*B_[0]; \
            vfloat2 q23_ = A_[3]*B_[3] + A_[2]*B_[2]; \
            vfloat2 qq_ = q01_ + q23_; dst = qq_.x + qq_.y; }
        #define SHIP(ring, hf, sl, V_) { \
            vfloat4 lo_ = {V_[0].x, V_[0].y, V_[1].x, V_[1].y}; \
            vfloat4 hi_ = {V_[2].x, V_[2].y, V_[3].x, V_[3].y}; \
            ring[hf][sl][0][lane] = lo_; ring[hf][sl][1][lane] = hi_; }
        #define RDU(dst, hf, sl) { \
            vfloat4 lo_ = ub[hf][sl][0][lane]; vfloat4 hi_ = ub[hf][sl][1][lane]; \
            vfloat2 t0_ = {lo_.x, lo_.y}; dst[0] = t0_; \
            vfloat2 t1_ = {lo_.z, lo_.w}; dst[1] = t1_; \
            vfloat2 t2_ = {hi_.x, hi_.y}; dst[2] = t2_; \
            vfloat2 t3_ = {hi_.z, hi_.w}; dst[3] = t3_; }

        // ---------- prologue ----------
        while (*vprod < 1) {}
        asm volatile("" ::: "memory");
        vfloat2 u0v[4], u1v[4], u2v[4];
        RDU(u0v, 0, 0); RDU(u1v, 0, 1); RDU(u2v, 0, 2);
        // t=0: exact
        float a0_0, a0_1;
        {
            vfloat2 r0v[4], T0v[4], D0v[4], base0c[4];
            #pragma unroll
            for (int j = 0; j < 4; ++j) r0v[j] = th2(h0v[j]);
            SHIP(rb, 0, 0, r0v); SHIP(hb, 0, 0, h0v);
            float p0, p1; HORIZ(p0, r0v, n0v); HORIZ(p1, r0v, n1v);
            wave_reduce2(p0, p1);
            a0_0 = RL63(p0); a0_1 = RL63(p1);
            #pragma unroll
            for (int j = 0; j < 4; ++j) { base0c[j] = h0v[j] * 0.8f + u0v[j]; basep[j] = base0c[j]; }
            #pragma unroll
            for (int j = 0; j < 4; ++j) { T0v[j] = th2(base0c[j]); D0v[j] = 1.0f - T0v[j]*T0v[j]; }
            // C1, A1
            float c10, c11; HORIZ(c10, T0v, n0v); HORIZ(c11, T0v, n1v);
            vfloat2 e0[4], e1[4];
            #pragma unroll
            for (int j = 0; j < 4; ++j) { e0[j] = D0v[j]*m0S[j]; e1[j] = D0v[j]*m1S[j]; }
            float q0, q1, q2, q3;
            HORIZ(q0, e0, n0v); HORIZ(q1, e1, n0v); HORIZ(q2, e0, n1v); HORIZ(q3, e1, n1v);
            wave_reduce2(c10, c11); wave_reduce4(q0, q1, q2, q3);
            float C1_0 = RL63(c10), C1_1 = RL63(c11);
            A00 = RL63(q0); A01 = RL63(q1); A10 = RL63(q2); A11 = RL63(q3);
            // C2 partials from beta1 = 0.8*base0 + u1 -> Tk0/Dk0
            #pragma unroll
            for (int j = 0; j < 4; ++j) {
                vfloat2 be = base0c[j] * 0.8f + u1v[j];
                vfloat2 T = th2(be); Tk0[j] = T; Dk0[j] = 1.0f - T*T;
            }
            HORIZ(cA0, Tk0, n0v); HORIZ(cA1, Tk0, n1v);
            wave_reduce2(cA0, cA1);
            // t=1 manual
            float w0 = a0_0, w1 = a0_1;
            float at0 = C1_0 + A00*w0 + A01*w1;
            float at1 = C1_1 + A10*w0 + A11*w1;
            vfloat2 ab0 = bc2(a0_0), ab1 = bc2(a0_1);
            vfloat2 h1v[4], r1v[4];
            #pragma unroll
            for (int j = 0; j < 4; ++j) {
                vfloat2 dl = ab0*m0S[j] + ab1*m1S[j];
                h1v[j] = basep[j] + dl;
                vfloat2 t1 = T0v[j]*dl;
                vfloat2 ee = dl - t1*dl;
                r1v[j] = D0v[j]*ee + T0v[j];
            }
            SHIP(hb, 0, 1, h1v); SHIP(rb, 0, 1, r1v);
            #pragma unroll
            for (int j = 0; j < 4; ++j) basep[j] = h1v[j]*0.8f + u1v[j];   // base_1
            #pragma unroll
            for (int j = 0; j < 4; ++j) {
                vfloat2 be = basep[j]*0.8f + u2v[j];                        // beta_2
                vfloat2 T = th2(be); Tk1[j] = T; Dk1[j] = 1.0f - T*T;
            }
            HORIZ(cB0, Tk1, n0v); HORIZ(cB1, Tk1, n1v);
            wave_reduce2(cB0, cB1);                                         // C_3
            C0cur = RL63(cA0); C1cur = RL63(cA1);                           // C_2
            a2_0 = a0_0; a2_1 = a0_1; a1_0 = at0; a1_1 = at1;
            #pragma unroll
            for (int j = 0; j < 4; ++j) ucur[j] = u2v[j];
        }

        // ---------- steady step macro ----------
        // S_: slot (compile-time), HF_: ring half, UH_/US_: u_{t+1} location,
        // SPIN_: extra cross-phase spin bound (0 = none), RLA_: A-readlane enable.
        #define CSTEP(S_, HF_, UH_, US_, SPIN_, RLA_) { \
            if (SPIN_) { while (*vprod < (SPIN_)) {} asm volatile("" ::: "memory"); } \
            vfloat2 unv[4]; RDU(unv, (UH_), (US_)); \
            float Cn0, Cn1; \
            if (((S_) & 1) == 0) { Cn0 = RL63(cB0); Cn1 = RL63(cB1); } \
            else                 { Cn0 = RL63(cA0); Cn1 = RL63(cA1); } \
            if (((S_) % 4) == 2 && (RLA_)) { \
                A00 = RL63(qa0); A01 = RL63(qa1); A10 = RL63(qa2); A11 = RL63(qa3); } \
            float w0 = __builtin_fmaf(0.8f, a2_0, a1_0); \
            float w1 = __builtin_fmaf(0.8f, a2_1, a1_1); \
            float at0 = __builtin_fmaf(A00, w0, __builtin_fmaf(A01, w1, C0cur)); \
            float at1 = __builtin_fmaf(A10, w0, __builtin_fmaf(A11, w1, C1cur)); \
            vfloat2 ab0 = bc2(a1_0), ab1 = bc2(a1_1); \
            vfloat2 wb0 = bc2(w0),  wb1 = bc2(w1); \
            vfloat2 hv[4], rv[4], Tn[4], Dn[4]; \
            _Pragma("unroll") \
            for (int j = 0; j < 4; ++j) { \
                vfloat2 dl = ab0*m0S[j] + ab1*m1S[j]; \
                hv[j] = basep[j] + dl; \
                vfloat2 ep = wb0*m0S[j] + wb1*m1S[j]; \
                vfloat2 Tp = ((S_) & 1) ? Tk1[j] : Tk0[j]; \
                vfloat2 Dp = ((S_) & 1) ? Dk1[j] : Dk0[j]; \
                vfloat2 t1 = Tp*ep; \
                vfloat2 ee = ep - t1*ep; \
                rv[j] = Dp*ee + Tp; \
            } \
            SHIP(hb, (HF_), (S_), hv); SHIP(rb, (HF_), (S_), rv); \
            _Pragma("unroll") \
            for (int j = 0; j < 4; ++j) { \
                basep[j] = hv[j]*0.8f + ucur[j]; \
                vfloat2 be = basep[j]*0.8f + unv[j]; \
                vfloat2 T = th2(be); \
                Tn[j] = T; Dn[j] = 1.0f - T*T; \
                if ((S_) & 1) { Tk1[j] = T; Dk1[j] = Dn[j]; } \
                else          { Tk0[j] = T; Dk0[j] = Dn[j]; } \
                ucur[j] = unv[j]; \
            } \
            float pc0, pc1; HORIZ(pc0, Tn, n0v); HORIZ(pc1, Tn, n1v); \
            if (((S_) & 1) == 0) { cA0 = pc0; cA1 = pc1; wave_reduce2(cA0, cA1); } \
            else                 { cB0 = pc0; cB1 = pc1; wave_reduce2(cB0, cB1); } \
            if (((S_) % 4) == 0) { \
                vfloat2 e0[4], e1[4]; \
                _Pragma("unroll") \
                for (int j = 0; j < 4; ++j) { e0[j] = Dn[j]*m0S[j]; e1[j] = Dn[j]*m1S[j]; } \
                HORIZ(qa0, e0, n0v); HORIZ(qa1, e1, n0v); \
                HORIZ(qa2, e0, n1v); HORIZ(qa3, e1, n1v); \
                wave_reduce4(qa0, qa1, qa2, qa3); \
            } \
            a2_0 = a1_0; a2_1 = a1_1; a1_0 = at0; a1_1 = at1; \
            C0cur = Cn0; C1cur = Cn1; }

        // phase 0: s=2..7 (s=0,1 done in prologue; s=2 skips A-readlane)
        CSTEP(2, 0, 0, 3, 0, 0)
        CSTEP(3, 0, 0, 4, 0, 1)
        CSTEP(4, 0, 0, 5, 0, 1)
        CSTEP(5, 0, 0, 6, 0, 1)
        CSTEP(6, 0, 0, 7, 0, 1)
        CSTEP(7, 0, 1, 0, 2, 1)
        asm volatile("s_waitcnt lgkmcnt(0)" ::: "memory");
        if (lane == 0) *vcons = 1;

        for (int p = 1; p < NPHASE - 1; ++p) {
            while (*vprod < p + 1) {}
            asm volatile("" ::: "memory");
            const int half = p & 1;
            CSTEP(0, half, half, 1, 0, 1)
            CSTEP(1, half, half, 2, 0, 1)
            CSTEP(2, half, half, 3, 0, 1)
            CSTEP(3, half, half, 4, 0, 1)
            CSTEP(4, half, half, 5, 0, 1)
            CSTEP(5, half, half, 6, 0, 1)
            CSTEP(6, half, half, 7, 0, 1)
            CSTEP(7, half, half ^ 1, 0, p + 2, 1)
            asm volatile("s_waitcnt lgkmcnt(0)" ::: "memory");
            if (lane == 0) *vcons = p + 1;
        }
        // phase 124 (half 0): last step's u_{t+1} clamps to u_999
        {
            while (*vprod < NPHASE) {}
            asm volatile("" ::: "memory");
            CSTEP(0, 0, 0, 1, 0, 1)
            CSTEP(1, 0, 0, 2, 0, 1)
            CSTEP(2, 0, 0, 3, 0, 1)
            CSTEP(3, 0, 0, 4, 0, 1)
            CSTEP(4, 0, 0, 5, 0, 1)
            CSTEP(5, 0, 0, 6, 0, 1)
            CSTEP(6, 0, 0, 7, 0, 1)
            CSTEP(7, 0, 0, 7, 0, 1)
            asm volatile("s_waitcnt lgkmcnt(0)" ::: "memory");
            if (lane == 0) *vcons = NPHASE;   // 125
        }
        // fin: h_1000 = base_999 + m~ a_999; r_1000 exact
        {
            vfloat2 ab0 = bc2(a1_0), ab1 = bc2(a1_1);
            vfloat2 hT[4], rT[4];
            #pragma unroll
            for (int j = 0; j < 4; ++j) {
                vfloat2 dl = ab0*m0S[j] + ab1*m1S[j];
                hT[j] = basep[j] + dl;
                rT[j] = th2(hT[j]);
            }
            vfloat4 rlo = {rT[0].x, rT[0].y, rT[1].x, rT[1].y};
            vfloat4 rhi = {rT[2].x, rT[2].y, rT[3].x, rT[3].y};
            rfin[0][lane] = rlo; rfin[1][lane] = rhi;
            vfloat4 hlo = {hT[0].x, hT[0].y, hT[1].x, hT[1].y};
            vfloat4 hhi = {hT[2].x, hT[2].y, hT[3].x, hT[3].y};
            hfin[0][lane] = hlo; hfin[1][lane] = hhi;
            asm volatile("s_waitcnt lgkmcnt(0)" ::: "memory");
            if (lane == 0) *vcons = NPHASE + 1;   // 126
        }
        #undef CSTEP
        #undef HORIZ
        #undef SHIP
        #undef RDU
    }
}

extern "C" void kernel_launch(void* const* d_in, const int* in_sizes, int n_in,
                              void* d_out, int out_size, void* d_ws, size_t ws_size,
                              hipStream_t stream) {
    const float* input = (const float*)d_in[0];
    const float* noise = (const float*)d_in[1];
    const float* wi    = (const float*)d_in[2];
    const float* si    = (const float*)d_in[3];
    const float* m     = (const float*)d_in[4];
    const float* n     = (const float*)d_in[5];
    const float* wo    = (const float*)d_in[6];
    const float* so    = (const float*)d_in[7];
    const float* h0    = (const float*)d_in[8];
    float* out = (float*)d_out;

    hipLaunchKernelGGL(lowrank_rnn_kernel, dim3(B_), dim3(128), 0, stream,
                       input, noise, wi, si, m, n, wo, so, h0, out);
}